// Round 1
// baseline (1358.570 us; speedup 1.0000x reference)
//
#include <hip/hip_runtime.h>

#define DEVI __device__ __forceinline__

typedef __bf16 bf16x8 __attribute__((ext_vector_type(8)));
typedef float f32x4 __attribute__((ext_vector_type(4)));
typedef unsigned short u16;

constexpr int B_ = 4;
constexpr int C_ = 1024;
constexpr int CI_ = 512;
constexpr int N_ = 16 * 28 * 28;   // 12544 = 98*128
constexpr int M_ = 8 * 14 * 14;    // 1568
constexpr int MP_ = 1664;          // 13*128 padded

DEVI u16 f2bf(float f) { __bf16 b = (__bf16)f; return __builtin_bit_cast(u16, b); }
DEVI float bf2f(u16 u) { return (float)__builtin_bit_cast(__bf16, u); }

#define GLOBAL_AS __attribute__((address_space(1)))
#define LDS_AS __attribute__((address_space(3)))

DEVI void load16(const u16* g, u16* l) {
  __builtin_amdgcn_global_load_lds((const GLOBAL_AS void*)g, (LDS_AS void*)l, 16, 0, 0);
}

// ---------------------------------------------------------------------------
// Universal TN GEMM: C[i,j] = sum_k A[i*K+k] * B[j*K+k]   (A: IxK, B: JxK, both
// row-major bf16 with K contiguous). 128x128 tile, BK=64, 256 threads, MFMA
// 16x16x32 bf16, global_load_lds width-16 staging (m97 structure).
// MODE 0: bf16 out = acc + e0[col]           (conv + bias)
// MODE 1: fp32 out = acc                     (attention logits)
// MODE 2: bf16 out = acc                     (PV)
// MODE 3: fp32 out = (acc+e0[row])*e1[row]*rsqrt(1+eps) + e2[row] + xres[idx]
// ---------------------------------------------------------------------------
template <int MODE>
__global__ __launch_bounds__(256)
void gemm_tn(const u16* __restrict__ A, const u16* __restrict__ Bm,
             void* __restrict__ Cp, int K, int ldc,
             const float* __restrict__ e0, const float* __restrict__ e1,
             const float* __restrict__ e2, const float* __restrict__ xres) {
  __shared__ u16 lA[128 * 64];
  __shared__ u16 lB[128 * 64];
  const int tid = threadIdx.x;
  const int lane = tid & 63;
  const int wr = ((tid >> 6) >> 1) * 64;  // wave row offset in tile
  const int wc = ((tid >> 6) & 1) * 64;   // wave col offset in tile
  const int i0 = blockIdx.y * 128;
  const int j0 = blockIdx.x * 128;

  f32x4 acc[4][4] = {};

  // staging: each thread loads 16B; row = tid/8 (+q*32), colbyte = (tid%8)*16
  const int srow = tid >> 3;
  const int scol = (tid & 7) * 8;
  const u16* Ag = A + (size_t)(i0 + srow) * K + scol;
  const u16* Bg = Bm + (size_t)(j0 + srow) * K + scol;
  u16* lAw = lA + srow * 64 + scol;  // byte offset == tid*16 (wave base + lane*16)
  u16* lBw = lB + srow * 64 + scol;

  const int lrow = lane & 15;
  const int lq = (lane >> 4) * 8;

  for (int k0 = 0; k0 < K; k0 += 64) {
    __syncthreads();
#pragma unroll
    for (int q = 0; q < 4; ++q) load16(Ag + (size_t)q * 32 * K + k0, lAw + q * 32 * 64);
#pragma unroll
    for (int q = 0; q < 4; ++q) load16(Bg + (size_t)q * 32 * K + k0, lBw + q * 32 * 64);
    __syncthreads();
#pragma unroll
    for (int ks = 0; ks < 2; ++ks) {
      bf16x8 af[4], bfr[4];
#pragma unroll
      for (int mi = 0; mi < 4; ++mi)
        af[mi] = *(const bf16x8*)&lA[(wr + mi * 16 + lrow) * 64 + ks * 32 + lq];
#pragma unroll
      for (int ni = 0; ni < 4; ++ni)
        bfr[ni] = *(const bf16x8*)&lB[(wc + ni * 16 + lrow) * 64 + ks * 32 + lq];
#pragma unroll
      for (int mi = 0; mi < 4; ++mi)
#pragma unroll
        for (int ni = 0; ni < 4; ++ni)
          acc[mi][ni] = __builtin_amdgcn_mfma_f32_16x16x32_bf16(af[mi], bfr[ni], acc[mi][ni], 0, 0, 0);
    }
  }

  // C/D layout (verified m89/m91): col = lane&15, row = (lane>>4)*4 + reg
  const int r0 = i0 + wr + ((lane >> 4) << 2);
  const int c0 = j0 + wc + (lane & 15);
  float* Cf = (float*)Cp;
  u16* Cs = (u16*)Cp;
#pragma unroll
  for (int mi = 0; mi < 4; ++mi) {
#pragma unroll
    for (int ni = 0; ni < 4; ++ni) {
      const int col = c0 + ni * 16;
#pragma unroll
      for (int r = 0; r < 4; ++r) {
        const int row = r0 + mi * 16 + r;
        const size_t idx = (size_t)row * ldc + col;
        float v = acc[mi][ni][r];
        if constexpr (MODE == 0) {
          Cs[idx] = f2bf(v + e0[col]);
        } else if constexpr (MODE == 1) {
          Cf[idx] = v;
        } else if constexpr (MODE == 2) {
          Cs[idx] = f2bf(v);
        } else {
          const float sc = e1[row] * rsqrtf(1.0f + 1e-5f);
          Cf[idx] = (v + e0[row]) * sc + e2[row] + xres[idx];
        }
      }
    }
  }
}

// x_b (C_, N_) fp32 -> Xt (N_, C_) bf16 (tiled transpose-cast)
__global__ __launch_bounds__(256)
void transpose_cast_x(const float* __restrict__ src, u16* __restrict__ dst) {
  __shared__ u16 tile[32][33];
  const int n0 = blockIdx.x * 32;
  const int c0 = blockIdx.y * 32;
  const int tx = threadIdx.x & 31;
  const int ty = threadIdx.x >> 5;  // 0..7
#pragma unroll
  for (int rr = 0; rr < 32; rr += 8)
    tile[ty + rr][tx] = f2bf(src[(size_t)(c0 + ty + rr) * N_ + n0 + tx]);
  __syncthreads();
#pragma unroll
  for (int rr = 0; rr < 32; rr += 8)
    dst[(size_t)(n0 + ty + rr) * C_ + c0 + tx] = tile[tx][ty + rr];
}

// generic bf16 transpose (R x Cc) -> (Cc x R); R,Cc multiples of 32
__global__ __launch_bounds__(256)
void transpose_bf16(const u16* __restrict__ src, u16* __restrict__ dst, int R, int Cc) {
  __shared__ u16 tile[32][33];
  const int c0 = blockIdx.x * 32;
  const int r0 = blockIdx.y * 32;
  const int tx = threadIdx.x & 31;
  const int ty = threadIdx.x >> 5;
#pragma unroll
  for (int rr = 0; rr < 32; rr += 8)
    tile[ty + rr][tx] = src[(size_t)(r0 + ty + rr) * Cc + c0 + tx];
  __syncthreads();
#pragma unroll
  for (int rr = 0; rr < 32; rr += 8)
    dst[(size_t)(c0 + ty + rr) * R + r0 + tx] = tile[tx][ty + rr];
}

// cast 4 weight matrices fp32->bf16 (each 512*1024 = 524288 elems)
__global__ __launch_bounds__(256)
void cast_weights(const float* s0, const float* s1, const float* s2, const float* s3,
                  u16* d0, u16* d1, u16* d2, u16* d3) {
  const int idx = blockIdx.x * 256 + threadIdx.x;
  const float* s;
  u16* d;
  switch (blockIdx.y) {
    case 0: s = s0; d = d0; break;
    case 1: s = s1; d = d1; break;
    case 2: s = s2; d = d2; break;
    default: s = s3; d = d3; break;
  }
  d[idx] = f2bf(s[idx]);
}

// maxpool2 over (T,H,W) on (N_, CI_) layout -> (MP_, CI_); rows >= M_ zeroed
__global__ __launch_bounds__(256)
void pool2(const u16* __restrict__ s0, u16* __restrict__ d0,
           const u16* __restrict__ s1, u16* __restrict__ d1) {
  const u16* src = blockIdx.y ? s1 : s0;
  u16* dst = blockIdx.y ? d1 : d0;
  const int idx = blockIdx.x * 256 + threadIdx.x;  // over MP_*CI_
  const int m = idx >> 9;
  const int ci = idx & 511;
  if (m >= M_) { dst[idx] = 0; return; }
  const int t = m / 196, r = m % 196, h = r / 14, w = r % 14;
  const int nb = 2 * t * 784 + 2 * h * 28 + 2 * w;
  float mx = -1e30f;
#pragma unroll
  for (int dt = 0; dt < 2; ++dt)
#pragma unroll
    for (int dh = 0; dh < 2; ++dh)
#pragma unroll
      for (int dw = 0; dw < 2; ++dw)
        mx = fmaxf(mx, bf2f(src[(size_t)(nb + dt * 784 + dh * 28 + dw) * CI_ + ci]));
  dst[idx] = f2bf(mx);
}

// row softmax over m<M_ of F (N_, MP_) fp32 -> P (N_, MP_) bf16 (pad cols = 0)
__global__ __launch_bounds__(256)
void softmax_k(const float* __restrict__ F, u16* __restrict__ P) {
  const int n = blockIdx.x;
  const float* row = F + (size_t)n * MP_;
  u16* prow = P + (size_t)n * MP_;
  const int tid = threadIdx.x;
  float v[7];
  float mx = -1e30f;
#pragma unroll
  for (int it = 0; it < 7; ++it) {
    const int j = tid + it * 256;
    v[it] = (j < M_) ? row[j] : -1e30f;
    mx = fmaxf(mx, v[it]);
  }
#pragma unroll
  for (int off = 32; off >= 1; off >>= 1) mx = fmaxf(mx, __shfl_xor(mx, off));
  __shared__ float redm[4], reds[4];
  const int wv = tid >> 6;
  if ((tid & 63) == 0) redm[wv] = mx;
  __syncthreads();
  mx = fmaxf(fmaxf(redm[0], redm[1]), fmaxf(redm[2], redm[3]));
  float s = 0.f;
#pragma unroll
  for (int it = 0; it < 7; ++it) {
    const int j = tid + it * 256;
    v[it] = (j < M_) ? __expf(v[it] - mx) : 0.f;
    s += v[it];
  }
#pragma unroll
  for (int off = 32; off >= 1; off >>= 1) s += __shfl_xor(s, off);
  if ((tid & 63) == 0) reds[wv] = s;
  __syncthreads();
  s = reds[0] + reds[1] + reds[2] + reds[3];
  const float inv = 1.f / s;
#pragma unroll
  for (int it = 0; it < 7; ++it) {
    const int j = tid + it * 256;
    if (j < MP_) prow[j] = f2bf(v[it] * inv);
  }
}

extern "C" void kernel_launch(void* const* d_in, const int* in_sizes, int n_in,
                              void* d_out, int out_size, void* d_ws, size_t ws_size,
                              hipStream_t stream) {
  (void)in_sizes; (void)n_in; (void)out_size; (void)ws_size;
  const float* x    = (const float*)d_in[0];
  const float* g_w  = (const float*)d_in[1];
  const float* g_b  = (const float*)d_in[2];
  const float* th_w = (const float*)d_in[3];
  const float* th_b = (const float*)d_in[4];
  const float* ph_w = (const float*)d_in[5];
  const float* ph_b = (const float*)d_in[6];
  const float* w_w  = (const float*)d_in[7];
  const float* w_b  = (const float*)d_in[8];
  const float* bn_g = (const float*)d_in[9];
  const float* bn_b = (const float*)d_in[10];
  float* out = (float*)d_out;

  char* ws = (char*)d_ws;
  size_t off = 0;
  auto alloc = [&](size_t bytes) -> void* {
    void* p = ws + off;
    off += (bytes + 255) & ~(size_t)255;
    return p;
  };
  u16* wgB = (u16*)alloc((size_t)CI_ * C_ * 2);
  u16* wtB = (u16*)alloc((size_t)CI_ * C_ * 2);
  u16* wpB = (u16*)alloc((size_t)CI_ * C_ * 2);
  u16* wwB = (u16*)alloc((size_t)C_ * CI_ * 2);
  u16* Xt  = (u16*)alloc((size_t)N_ * C_ * 2);    // (N, C) bf16
  u16* Th  = (u16*)alloc((size_t)N_ * CI_ * 2);   // theta_x (N, CI)
  u16* Gf  = (u16*)alloc((size_t)N_ * CI_ * 2);   // g full-res (N, CI)
  u16* Pf  = (u16*)alloc((size_t)N_ * CI_ * 2);   // phi full-res (N, CI)
  u16* Yb  = (u16*)alloc((size_t)N_ * CI_ * 2);   // y (N, CI)
  u16* Gp  = (u16*)alloc((size_t)MP_ * CI_ * 2);  // g pooled (MP, CI)
  u16* Pp  = (u16*)alloc((size_t)MP_ * CI_ * 2);  // phi pooled (MP, CI)
  u16* Gp2 = (u16*)alloc((size_t)CI_ * MP_ * 2);  // g pooled transposed (CI, MP)
  float* Fb = (float*)alloc((size_t)N_ * MP_ * 4);  // logits (N, MP) fp32
  u16* Pb  = (u16*)alloc((size_t)N_ * MP_ * 2);     // softmax probs (N, MP) bf16

  const dim3 blk(256);
  cast_weights<<<dim3(2048, 4), blk, 0, stream>>>(g_w, th_w, ph_w, w_w, wgB, wtB, wpB, wwB);

  for (int b = 0; b < B_; ++b) {
    const float* xb = x + (size_t)b * C_ * N_;
    float* ob = out + (size_t)b * C_ * N_;
    transpose_cast_x<<<dim3(N_ / 32, C_ / 32), blk, 0, stream>>>(xb, Xt);
    // 1x1 convs: (N,CI) = Xt(N,C) . W(CI,C)^T + bias
    gemm_tn<0><<<dim3(CI_ / 128, N_ / 128), blk, 0, stream>>>(Xt, wtB, Th, C_, CI_, th_b, nullptr, nullptr, nullptr);
    gemm_tn<0><<<dim3(CI_ / 128, N_ / 128), blk, 0, stream>>>(Xt, wgB, Gf, C_, CI_, g_b, nullptr, nullptr, nullptr);
    gemm_tn<0><<<dim3(CI_ / 128, N_ / 128), blk, 0, stream>>>(Xt, wpB, Pf, C_, CI_, ph_b, nullptr, nullptr, nullptr);
    pool2<<<dim3(MP_ * CI_ / 256, 2), blk, 0, stream>>>(Gf, Gp, Pf, Pp);
    transpose_bf16<<<dim3(CI_ / 32, MP_ / 32), blk, 0, stream>>>(Gp, Gp2, MP_, CI_);
    // logits: F(N,MP) = Th(N,CI) . Pp(MP,CI)^T
    gemm_tn<1><<<dim3(MP_ / 128, N_ / 128), blk, 0, stream>>>(Th, Pp, Fb, CI_, MP_, nullptr, nullptr, nullptr, nullptr);
    softmax_k<<<dim3(N_), blk, 0, stream>>>(Fb, Pb);
    // y: (N,CI) = P(N,MP) . Gp2(CI,MP)^T
    gemm_tn<2><<<dim3(CI_ / 128, N_ / 128), blk, 0, stream>>>(Pb, Gp2, Yb, MP_, CI_, nullptr, nullptr, nullptr, nullptr);
    // out: (C,N) = Ww(C,CI) . Yb(N,CI)^T, epilogue bias/BN/residual
    gemm_tn<3><<<dim3(N_ / 128, C_ / 128), blk, 0, stream>>>(wwB, Yb, ob, CI_, N_, w_b, bn_g, bn_b, xb);
  }
}

// Round 2
// 1189.424 us; speedup vs baseline: 1.1422x; 1.1422x over previous
//
#include <hip/hip_runtime.h>

#define DEVI __device__ __forceinline__

typedef __bf16 bf16x8 __attribute__((ext_vector_type(8)));
typedef float f32x4 __attribute__((ext_vector_type(4)));
typedef unsigned short u16;
typedef long long i64;

constexpr int B_ = 4;
constexpr int C_ = 1024;
constexpr int CI_ = 512;
constexpr int C3_ = 3 * CI_;       // 1536 fused conv output cols
constexpr int N_ = 16 * 28 * 28;   // 12544 = 98*128
constexpr int M_ = 8 * 14 * 14;    // 1568
constexpr int MP_ = 1664;          // 13*128 padded

DEVI u16 f2bf(float f) { __bf16 b = (__bf16)f; return __builtin_bit_cast(u16, b); }
DEVI float bf2f(u16 u) { return (float)__builtin_bit_cast(__bf16, u); }

#define GLOBAL_AS __attribute__((address_space(1)))
#define LDS_AS __attribute__((address_space(3)))

DEVI void load16(const u16* g, u16* l) {
  __builtin_amdgcn_global_load_lds((const GLOBAL_AS void*)g, (LDS_AS void*)l, 16, 0, 0);
}

// ---------------------------------------------------------------------------
// Universal batched TN GEMM: C[i,j] = sum_k A[i*lda+k] * B[j*ldb+k]
// (both operands K-contiguous bf16). 128x128 tile, BK=64, 256 threads,
// MFMA 16x16x32 bf16, global_load_lds width-16 staging (m97 structure).
// blockIdx.z = batch; sA/sB/sC/sX are per-batch element strides.
// MODE 0: bf16 out = acc + e0[col]           (fused conv + bias)
// MODE 1: bf16 out = acc                     (logits / PV)
// MODE 3: fp32 out = (acc+e0[row])*e1[row]*rsqrt(1+eps) + e2[row] + xres[idx]
// ---------------------------------------------------------------------------
template <int MODE>
__global__ __launch_bounds__(256)
void gemm_tn(const u16* __restrict__ A, const u16* __restrict__ Bm,
             void* __restrict__ Cp, int K, int lda, int ldb, int ldc,
             i64 sA, i64 sB, i64 sC,
             const float* __restrict__ e0, const float* __restrict__ e1,
             const float* __restrict__ e2, const float* __restrict__ xres, i64 sX) {
  __shared__ u16 lA[128 * 64];
  __shared__ u16 lB[128 * 64];
  const int b = blockIdx.z;
  A += (size_t)b * sA;
  Bm += (size_t)b * sB;
  const size_t cbase = (size_t)b * sC;
  xres += (MODE == 3) ? (size_t)b * sX : 0;

  const int tid = threadIdx.x;
  const int lane = tid & 63;
  const int wr = ((tid >> 6) >> 1) * 64;  // wave row offset in tile
  const int wc = ((tid >> 6) & 1) * 64;   // wave col offset in tile
  const int i0 = blockIdx.y * 128;
  const int j0 = blockIdx.x * 128;

  f32x4 acc[4][4] = {};

  // staging: each thread loads 16B; row = tid/8 (+q*32), col = (tid%8)*8 elems
  const int srow = tid >> 3;
  const int scol = (tid & 7) * 8;
  const u16* Ag = A + (size_t)(i0 + srow) * lda + scol;
  const u16* Bg = Bm + (size_t)(j0 + srow) * ldb + scol;
  u16* lAw = lA + srow * 64 + scol;  // byte offset == tid*16 (wave base + lane*16)
  u16* lBw = lB + srow * 64 + scol;

  const int lrow = lane & 15;
  const int lq = (lane >> 4) * 8;

  for (int k0 = 0; k0 < K; k0 += 64) {
    __syncthreads();
#pragma unroll
    for (int q = 0; q < 4; ++q) load16(Ag + (size_t)q * 32 * lda + k0, lAw + q * 32 * 64);
#pragma unroll
    for (int q = 0; q < 4; ++q) load16(Bg + (size_t)q * 32 * ldb + k0, lBw + q * 32 * 64);
    __syncthreads();
#pragma unroll
    for (int ks = 0; ks < 2; ++ks) {
      bf16x8 af[4], bfr[4];
#pragma unroll
      for (int mi = 0; mi < 4; ++mi)
        af[mi] = *(const bf16x8*)&lA[(wr + mi * 16 + lrow) * 64 + ks * 32 + lq];
#pragma unroll
      for (int ni = 0; ni < 4; ++ni)
        bfr[ni] = *(const bf16x8*)&lB[(wc + ni * 16 + lrow) * 64 + ks * 32 + lq];
#pragma unroll
      for (int mi = 0; mi < 4; ++mi)
#pragma unroll
        for (int ni = 0; ni < 4; ++ni)
          acc[mi][ni] = __builtin_amdgcn_mfma_f32_16x16x32_bf16(af[mi], bfr[ni], acc[mi][ni], 0, 0, 0);
    }
  }

  // C/D layout (verified m89/m91): col = lane&15, row = (lane>>4)*4 + reg
  const int r0 = i0 + wr + ((lane >> 4) << 2);
  const int c0 = j0 + wc + (lane & 15);
  float* Cf = (float*)Cp;
  u16* Cs = (u16*)Cp;
#pragma unroll
  for (int mi = 0; mi < 4; ++mi) {
#pragma unroll
    for (int ni = 0; ni < 4; ++ni) {
      const int col = c0 + ni * 16;
#pragma unroll
      for (int r = 0; r < 4; ++r) {
        const int row = r0 + mi * 16 + r;
        const size_t idx = cbase + (size_t)row * ldc + col;
        float v = acc[mi][ni][r];
        if constexpr (MODE == 0) {
          Cs[idx] = f2bf(v + e0[col]);
        } else if constexpr (MODE == 1) {
          Cs[idx] = f2bf(v);
        } else {
          const float sc = e1[row] * rsqrtf(1.0f + 1e-5f);
          Cf[idx] = (v + e0[row]) * sc + e2[row] + xres[(size_t)row * ldc + col];
        }
      }
    }
  }
}

// x (b,C,N) fp32 -> Xt (b,N,C) bf16 (tiled transpose-cast); z = batch
__global__ __launch_bounds__(256)
void transpose_cast_x(const float* __restrict__ src, u16* __restrict__ dst) {
  __shared__ u16 tile[32][33];
  const size_t so = (size_t)blockIdx.z * C_ * N_;
  const int n0 = blockIdx.x * 32;
  const int c0 = blockIdx.y * 32;
  const int tx = threadIdx.x & 31;
  const int ty = threadIdx.x >> 5;  // 0..7
#pragma unroll
  for (int rr = 0; rr < 32; rr += 8)
    tile[ty + rr][tx] = f2bf(src[so + (size_t)(c0 + ty + rr) * N_ + n0 + tx]);
  __syncthreads();
#pragma unroll
  for (int rr = 0; rr < 32; rr += 8)
    dst[so + (size_t)(n0 + ty + rr) * C_ + c0 + tx] = tile[tx][ty + rr];
}

// bf16 transpose per batch: src (b, MP_, CI_) -> dst (b, CI_, MP_)
__global__ __launch_bounds__(256)
void transpose_bf16(const u16* __restrict__ src, u16* __restrict__ dst) {
  __shared__ u16 tile[32][33];
  const int b = blockIdx.z;
  const int c0 = blockIdx.x * 32;  // over CI_
  const int r0 = blockIdx.y * 32;  // over MP_
  const int tx = threadIdx.x & 31;
  const int ty = threadIdx.x >> 5;
#pragma unroll
  for (int rr = 0; rr < 32; rr += 8)
    tile[ty + rr][tx] = src[(size_t)b * MP_ * CI_ + (size_t)(r0 + ty + rr) * CI_ + c0 + tx];
  __syncthreads();
#pragma unroll
  for (int rr = 0; rr < 32; rr += 8)
    dst[(size_t)b * CI_ * MP_ + (size_t)(c0 + ty + rr) * MP_ + r0 + tx] = tile[tx][ty + rr];
}

// cast weights fp32->bf16 into fused layout: wcat rows [theta; g; phi], plus Ww
__global__ __launch_bounds__(256)
void cast_weights(const float* s0, const float* s1, const float* s2, const float* s3,
                  u16* d0, u16* d1, u16* d2, u16* d3) {
  const int idx = blockIdx.x * 256 + threadIdx.x;  // 524288 elems each
  const float* s;
  u16* d;
  switch (blockIdx.y) {
    case 0: s = s0; d = d0; break;
    case 1: s = s1; d = d1; break;
    case 2: s = s2; d = d2; break;
    default: s = s3; d = d3; break;
  }
  d[idx] = f2bf(s[idx]);
}

// pack [theta_b; g_b; phi_b] -> ebias fp32[1536]
__global__ __launch_bounds__(256)
void concat_bias(const float* tb, const float* gb, const float* pb, float* dst) {
  const int i = blockIdx.x * 256 + threadIdx.x;
  if (i >= C3_) return;
  dst[i] = (i < CI_) ? tb[i] : (i < 2 * CI_) ? gb[i - CI_] : pb[i - 2 * CI_];
}

// maxpool2 over (T,H,W): reads CO (b, N_, C3_) at col offset 512(g)/1024(phi),
// writes (b, MP_, CI_); pad rows (m >= M_) zeroed. grid: (MP_*CI_/256, 2, G)
__global__ __launch_bounds__(256)
void pool2(const u16* __restrict__ CO, u16* __restrict__ Gp, u16* __restrict__ Pp) {
  const int b = blockIdx.z;
  const int which = blockIdx.y;  // 0 = g, 1 = phi
  const u16* src = CO + (size_t)b * N_ * C3_ + CI_ + which * CI_;
  u16* dst = (which ? Pp : Gp) + (size_t)b * MP_ * CI_;
  const int idx = blockIdx.x * 256 + threadIdx.x;  // over MP_*CI_
  const int m = idx >> 9;
  const int ci = idx & 511;
  if (m >= M_) { dst[idx] = 0; return; }
  const int t = m / 196, r = m % 196, h = r / 14, w = r % 14;
  const int nb = 2 * t * 784 + 2 * h * 28 + 2 * w;
  float mx = -1e30f;
#pragma unroll
  for (int dt = 0; dt < 2; ++dt)
#pragma unroll
    for (int dh = 0; dh < 2; ++dh)
#pragma unroll
      for (int dw = 0; dw < 2; ++dw)
        mx = fmaxf(mx, bf2f(src[(size_t)(nb + dt * 784 + dh * 28 + dw) * C3_ + ci]));
  dst[idx] = f2bf(mx);
}

// in-place row softmax (bf16) over m<M_ of F (b, N_, MP_); pad cols -> 0
__global__ __launch_bounds__(256)
void softmax_k(u16* __restrict__ F) {
  u16* row = F + ((size_t)blockIdx.y * N_ + blockIdx.x) * MP_;
  const int tid = threadIdx.x;
  float v[7];
  float mx = -1e30f;
#pragma unroll
  for (int it = 0; it < 7; ++it) {
    const int j = tid + it * 256;
    v[it] = (j < M_) ? bf2f(row[j]) : -1e30f;
    mx = fmaxf(mx, v[it]);
  }
#pragma unroll
  for (int off = 32; off >= 1; off >>= 1) mx = fmaxf(mx, __shfl_xor(mx, off));
  __shared__ float redm[4], reds[4];
  const int wv = tid >> 6;
  if ((tid & 63) == 0) redm[wv] = mx;
  __syncthreads();
  mx = fmaxf(fmaxf(redm[0], redm[1]), fmaxf(redm[2], redm[3]));
  float s = 0.f;
#pragma unroll
  for (int it = 0; it < 7; ++it) {
    const int j = tid + it * 256;
    v[it] = (j < M_) ? __expf(v[it] - mx) : 0.f;
    s += v[it];
  }
#pragma unroll
  for (int off = 32; off >= 1; off >>= 1) s += __shfl_xor(s, off);
  if ((tid & 63) == 0) reds[wv] = s;
  __syncthreads();
  s = reds[0] + reds[1] + reds[2] + reds[3];
  const float inv = 1.f / s;
#pragma unroll
  for (int it = 0; it < 7; ++it) {
    const int j = tid + it * 256;
    if (j < MP_) row[j] = f2bf(v[it] * inv);
  }
}

extern "C" void kernel_launch(void* const* d_in, const int* in_sizes, int n_in,
                              void* d_out, int out_size, void* d_ws, size_t ws_size,
                              hipStream_t stream) {
  (void)in_sizes; (void)n_in; (void)out_size;
  const float* x    = (const float*)d_in[0];
  const float* g_w  = (const float*)d_in[1];
  const float* g_b  = (const float*)d_in[2];
  const float* th_w = (const float*)d_in[3];
  const float* th_b = (const float*)d_in[4];
  const float* ph_w = (const float*)d_in[5];
  const float* ph_b = (const float*)d_in[6];
  const float* w_w  = (const float*)d_in[7];
  const float* w_b  = (const float*)d_in[8];
  const float* bn_g = (const float*)d_in[9];
  const float* bn_b = (const float*)d_in[10];
  float* out = (float*)d_out;

  auto align256 = [](size_t b) { return (b + 255) & ~(size_t)255; };
  const size_t fixed_bytes = align256((size_t)C3_ * C_ * 2) + align256((size_t)C_ * CI_ * 2) +
                             align256((size_t)C3_ * 4);
  const size_t per_batch = align256((size_t)N_ * C_ * 2)    // Xt
                         + align256((size_t)N_ * C3_ * 2)   // CO
                         + align256((size_t)N_ * MP_ * 2)   // F / P
                         + align256((size_t)N_ * CI_ * 2)   // Yb
                         + 3 * align256((size_t)MP_ * CI_ * 2);  // Gp, Pp, Gp2
  int G = 4;
  while (G > 1 && fixed_bytes + (size_t)G * per_batch > ws_size) G >>= 1;

  char* ws = (char*)d_ws;
  size_t off = 0;
  auto alloc = [&](size_t bytes) -> void* {
    void* p = ws + off;
    off += align256(bytes);
    return p;
  };
  u16* wcat = (u16*)alloc((size_t)C3_ * C_ * 2);   // rows: [theta; g; phi]
  u16* wwB  = (u16*)alloc((size_t)C_ * CI_ * 2);
  float* eb = (float*)alloc((size_t)C3_ * 4);
  u16* Xt  = (u16*)alloc((size_t)G * N_ * C_ * 2);
  u16* CO  = (u16*)alloc((size_t)G * N_ * C3_ * 2);
  u16* Fb  = (u16*)alloc((size_t)G * N_ * MP_ * 2);  // logits, then probs in-place
  u16* Yb  = (u16*)alloc((size_t)G * N_ * CI_ * 2);
  u16* Gp  = (u16*)alloc((size_t)G * MP_ * CI_ * 2);
  u16* Pp  = (u16*)alloc((size_t)G * MP_ * CI_ * 2);
  u16* Gp2 = (u16*)alloc((size_t)G * CI_ * MP_ * 2);

  const dim3 blk(256);
  cast_weights<<<dim3(2048, 4), blk, 0, stream>>>(
      th_w, g_w, ph_w, w_w, wcat, wcat + (size_t)CI_ * C_, wcat + (size_t)2 * CI_ * C_, wwB);
  concat_bias<<<dim3(6), blk, 0, stream>>>(th_b, g_b, ph_b, eb);

  for (int bg = 0; bg < B_; bg += G) {
    const float* xg = x + (size_t)bg * C_ * N_;
    float* og = out + (size_t)bg * C_ * N_;
    transpose_cast_x<<<dim3(N_ / 32, C_ / 32, G), blk, 0, stream>>>(xg, Xt);
    // fused 1x1 convs: CO(G*N, C3) = Xt(G*N, C) . wcat(C3, C)^T + eb  (batches stacked)
    gemm_tn<0><<<dim3(C3_ / 128, G * N_ / 128, 1), blk, 0, stream>>>(
        Xt, wcat, CO, C_, C_, C_, C3_, 0, 0, 0, eb, nullptr, nullptr, nullptr, 0);
    pool2<<<dim3(MP_ * CI_ / 256, 2, G), blk, 0, stream>>>(CO, Gp, Pp);
    transpose_bf16<<<dim3(CI_ / 32, MP_ / 32, G), blk, 0, stream>>>(Gp, Gp2);
    // logits: F(b; N, MP) = Th(b; N, CI [lda=C3]) . Pp(b; MP, CI)^T
    gemm_tn<1><<<dim3(MP_ / 128, N_ / 128, G), blk, 0, stream>>>(
        CO, Pp, Fb, CI_, C3_, CI_, MP_,
        (i64)N_ * C3_, (i64)MP_ * CI_, (i64)N_ * MP_, nullptr, nullptr, nullptr, nullptr, 0);
    softmax_k<<<dim3(N_, G), blk, 0, stream>>>(Fb);
    // y: Yb(b; N, CI) = P(b; N, MP) . Gp2(b; CI, MP)^T
    gemm_tn<1><<<dim3(CI_ / 128, N_ / 128, G), blk, 0, stream>>>(
        Fb, Gp2, Yb, MP_, MP_, MP_, CI_,
        (i64)N_ * MP_, (i64)CI_ * MP_, (i64)N_ * CI_, nullptr, nullptr, nullptr, nullptr, 0);
    // out: (b; C, N) = Ww(C, CI) . Yb(b; N, CI)^T, epilogue bias/BN/residual
    gemm_tn<3><<<dim3(N_ / 128, C_ / 128, G), blk, 0, stream>>>(
        wwB, Yb, og, CI_, CI_, CI_, N_,
        0, (i64)N_ * CI_, (i64)C_ * N_, w_b, bn_g, bn_b, xg, (i64)C_ * N_);
  }
}